// Round 5
// baseline (400.765 us; speedup 1.0000x reference)
//
#include <hip/hip_runtime.h>
#include <hip/hip_bf16.h>

#define GN 8192
#define KD 256
#define OD 64
#define LOG2E 1.44269504f
#define ASTR 260   // LDS row stride (ints): 1040B, 16B-aligned, 2-way bank alias (free)
#define NCH 16     // 16 chunks x 256 j = 4096-j slice per block

typedef __attribute__((ext_vector_type(8))) short bf16x8;
typedef __attribute__((ext_vector_type(4))) float f32x4;

__device__ __forceinline__ float fexp2(float x) {
#if __has_builtin(__builtin_amdgcn_exp2f)
  return __builtin_amdgcn_exp2f(x);
#else
  return exp2f(x);
#endif
}

// async global->LDS, 16B/lane: lane i of the wave lands at ldsbase + i*16.
__device__ __forceinline__ void async_cp16(const void* g, void* l) {
  __builtin_amdgcn_global_load_lds(
      (const __attribute__((address_space(1))) unsigned int*)g,
      (__attribute__((address_space(3))) unsigned int*)l, 16, 0, 0);
}

// ---------------------------------------------------------------------------
// Kernel 1: h = input @ W (fp32). Emits hT (bf16 [OD][GN]), f1p/f2p fp32
// pre-scaled by log2(e), and the 3 scalar e-outputs.
// ---------------------------------------------------------------------------
__global__ __launch_bounds__(256) void gat_k1(
    const float* __restrict__ input, const float* __restrict__ W,
    const float* __restrict__ a, __hip_bfloat16* __restrict__ hT,
    float* __restrict__ f1p, float* __restrict__ f2p, float* __restrict__ out)
{
  __shared__ float Wl[KD * OD];        // 64 KB, [k][c]
  __shared__ float inT[KD * 33];       // [k][r], pad 33
  __shared__ float red1[8][32];
  __shared__ float red2[8][32];
  __shared__ float s1row[32];
  __shared__ float s2row[32];

  const int tid = threadIdx.x;
  const int i0 = blockIdx.x * 32;

  for (int idx = tid; idx < KD * OD / 4; idx += 256)
    ((float4*)Wl)[idx] = ((const float4*)W)[idx];

#pragma unroll
  for (int it = 0; it < 8; ++it) {
    int idx = tid + it * 256;
    int r = idx >> 6, k4 = idx & 63;
    float4 v = *(const float4*)(input + (long)(i0 + r) * KD + k4 * 4);
    inT[(k4 * 4 + 0) * 33 + r] = v.x;
    inT[(k4 * 4 + 1) * 33 + r] = v.y;
    inT[(k4 * 4 + 2) * 33 + r] = v.z;
    inT[(k4 * 4 + 3) * 33 + r] = v.w;
  }
  __syncthreads();

  const int r = tid & 31;
  const int cg = tid >> 5;
  float acc[8];
#pragma unroll
  for (int c = 0; c < 8; ++c) acc[c] = 0.f;

#pragma unroll 4
  for (int k = 0; k < KD; ++k) {
    float inv = inT[k * 33 + r];
    float4 wa = *(const float4*)&Wl[k * 64 + cg * 8];
    float4 wb = *(const float4*)&Wl[k * 64 + cg * 8 + 4];
    acc[0] += inv * wa.x; acc[1] += inv * wa.y;
    acc[2] += inv * wa.z; acc[3] += inv * wa.w;
    acc[4] += inv * wb.x; acc[5] += inv * wb.y;
    acc[6] += inv * wb.z; acc[7] += inv * wb.w;
  }

#pragma unroll
  for (int c = 0; c < 8; ++c)
    hT[(long)(cg * 8 + c) * GN + i0 + r] = __float2bfloat16(acc[c]);

  float s1 = 0.f, s2 = 0.f;
#pragma unroll
  for (int c = 0; c < 8; ++c) {
    s1 += acc[c] * a[cg * 8 + c];
    s2 += acc[c] * a[OD + cg * 8 + c];
  }
  red1[cg][r] = s1; red2[cg][r] = s2;
  __syncthreads();
  if (tid < 32) {
    float f1 = 0.f, f2 = 0.f;
#pragma unroll
    for (int g = 0; g < 8; ++g) { f1 += red1[g][tid]; f2 += red2[g][tid]; }
    s1row[tid] = f1; s2row[tid] = f2;
    f1p[i0 + tid] = f1 * LOG2E;
    f2p[i0 + tid] = f2 * LOG2E;
  }
  __syncthreads();
  if (blockIdx.x == 0 && tid == 0) {
    float e12 = s1row[1] + s2row[2];
    float e13 = s1row[1] + s2row[3];
    float e32 = s1row[3] + s2row[2];
    out[(long)GN * OD + 0] = fmaxf(e12, 0.01f * e12);
    out[(long)GN * OD + 1] = fmaxf(e13, 0.01f * e13);
    out[(long)GN * OD + 2] = fmaxf(e32, 0.01f * e32);
  }
}

// ---------------------------------------------------------------------------
// Kernel 2: fused mask+softmax(no-max)+alpha@h, partial over a 4096-j slice.
// 1024 blocks = 512 row-groups x 2 j-slices; 4 blocks/CU (LDS overlaid).
// adj staged via async global_load_lds dbuf; B-frags (hT) rotate through
// registers across the barrier; partial num/den written to gmem.
// ---------------------------------------------------------------------------
__global__ __launch_bounds__(256, 4) void gat_k2(
    const int* __restrict__ adj, const __hip_bfloat16* __restrict__ hT,
    const float* __restrict__ f1p, const float* __restrict__ f2p,
    float* __restrict__ pn, float* __restrict__ pd)
{
  __shared__ int smem[2 * 16 * ASTR];  // 33.3 KB: adj dbuf; epilogue overlays pb/sb
  float* pb = (float*)smem;            // [4][16][68]
  float* sb = pb + 4 * 16 * 68;        // [4][16]

  const int tid = threadIdx.x;
  const int lane = tid & 63;
  const int wv = tid >> 6;             // wave 0..3 -> k-steps {2wv, 2wv+1}
  const int tn = lane & 15;
  const int quad = lane >> 4;
  const int rg = blockIdx.x >> 1;
  const int js = blockIdx.x & 1;
  const int i0 = rg * 16;
  const int jbase = js * 4096;

  const float f1r = f1p[i0 + tn];
  const int jo0 = (2 * wv) * 32 + quad * 8;
  const int jo1 = jo0 + 32;
  const __hip_bfloat16* hbase = hT + (long)tn * GN + jbase;
  const float* fpb = f2p + jbase;

  // staging: wave wv stages rows 4wv..4wv+3; lane covers 16B of the 1KB row
  const int srow = wv * 4;
  const int* g0 = adj + (long)(i0 + srow + 0) * GN + jbase + lane * 4;
  const int* g1 = adj + (long)(i0 + srow + 1) * GN + jbase + lane * 4;
  const int* g2 = adj + (long)(i0 + srow + 2) * GN + jbase + lane * 4;
  const int* g3 = adj + (long)(i0 + srow + 3) * GN + jbase + lane * 4;

  f32x4 acc[4];
#pragma unroll
  for (int nf = 0; nf < 4; ++nf) acc[nf] = (f32x4){0.f, 0.f, 0.f, 0.f};
  f32x4 accS = (f32x4){0.f, 0.f, 0.f, 0.f};

  bf16x8 ones;  // ones in column n==0 -> row sums via MFMA
  {
    short ov = (tn == 0) ? (short)0x3F80 : (short)0;
#pragma unroll
    for (int i = 0; i < 8; ++i) ones[i] = ov;
  }

  // prologue: async-stage chunk 0 into buf 0; prefetch B-frags for chunk 0
  async_cp16(g0, &smem[(srow + 0) * ASTR]);
  async_cp16(g1, &smem[(srow + 1) * ASTR]);
  async_cp16(g2, &smem[(srow + 2) * ASTR]);
  async_cp16(g3, &smem[(srow + 3) * ASTR]);
  bf16x8 B0[4], B1[4];
#pragma unroll
  for (int nf = 0; nf < 4; ++nf) {
    B0[nf] = *(const bf16x8*)(hbase + (long)nf * (16 * GN) + jo0);
    B1[nf] = *(const bf16x8*)(hbase + (long)nf * (16 * GN) + jo1);
  }
  __syncthreads();   // drains async chunk-0 stage (+B0/B1 in flight done)

  for (int c = 0; c < NCH; ++c) {
    const int cur = (c & 1) * (16 * ASTR);
    const int nxt = ((c & 1) ^ 1) * (16 * ASTR);
    if (c + 1 < NCH) {  // fire-and-forget stage of chunk c+1
      async_cp16(g0 + (c + 1) * 256, &smem[nxt + (srow + 0) * ASTR]);
      async_cp16(g1 + (c + 1) * 256, &smem[nxt + (srow + 1) * ASTR]);
      async_cp16(g2 + (c + 1) * 256, &smem[nxt + (srow + 2) * ASTR]);
      async_cp16(g3 + (c + 1) * 256, &smem[nxt + (srow + 3) * ASTR]);
    }

    // f2 for chunk c (hot 1KB, issued early to overlap the LDS reads)
    const float4 f20 = *(const float4*)(fpb + c * 256 + jo0);
    const float4 f21 = *(const float4*)(fpb + c * 256 + jo0 + 4);
    const float4 f22 = *(const float4*)(fpb + c * 256 + jo1);
    const float4 f23 = *(const float4*)(fpb + c * 256 + jo1 + 4);
    // A-source adj from staged LDS
    const int4 a0 = *(const int4*)&smem[cur + tn * ASTR + jo0];
    const int4 a1 = *(const int4*)&smem[cur + tn * ASTR + jo0 + 4];
    const int4 a2 = *(const int4*)&smem[cur + tn * ASTR + jo1];
    const int4 a3 = *(const int4*)&smem[cur + tn * ASTR + jo1 + 4];

    union { bf16x8 v; unsigned u[4]; } w0, w1;
    {
      float e0 = f1r + f20.x, e1 = f1r + f20.y, e2 = f1r + f20.z, e3 = f1r + f20.w;
      float e4 = f1r + f21.x, e5 = f1r + f21.y, e6 = f1r + f21.z, e7 = f1r + f21.w;
      float v0 = fexp2((a0.x > 0) ? fmaxf(e0, 0.01f * e0) : -256.f);
      float v1 = fexp2((a0.y > 0) ? fmaxf(e1, 0.01f * e1) : -256.f);
      float v2 = fexp2((a0.z > 0) ? fmaxf(e2, 0.01f * e2) : -256.f);
      float v3 = fexp2((a0.w > 0) ? fmaxf(e3, 0.01f * e3) : -256.f);
      float v4 = fexp2((a1.x > 0) ? fmaxf(e4, 0.01f * e4) : -256.f);
      float v5 = fexp2((a1.y > 0) ? fmaxf(e5, 0.01f * e5) : -256.f);
      float v6 = fexp2((a1.z > 0) ? fmaxf(e6, 0.01f * e6) : -256.f);
      float v7 = fexp2((a1.w > 0) ? fmaxf(e7, 0.01f * e7) : -256.f);
      w0.u[0] = __builtin_amdgcn_perm(__float_as_uint(v1), __float_as_uint(v0), 0x07060302u);
      w0.u[1] = __builtin_amdgcn_perm(__float_as_uint(v3), __float_as_uint(v2), 0x07060302u);
      w0.u[2] = __builtin_amdgcn_perm(__float_as_uint(v5), __float_as_uint(v4), 0x07060302u);
      w0.u[3] = __builtin_amdgcn_perm(__float_as_uint(v7), __float_as_uint(v6), 0x07060302u);
    }
    {
      float e0 = f1r + f22.x, e1 = f1r + f22.y, e2 = f1r + f22.z, e3 = f1r + f22.w;
      float e4 = f1r + f23.x, e5 = f1r + f23.y, e6 = f1r + f23.z, e7 = f1r + f23.w;
      float v0 = fexp2((a2.x > 0) ? fmaxf(e0, 0.01f * e0) : -256.f);
      float v1 = fexp2((a2.y > 0) ? fmaxf(e1, 0.01f * e1) : -256.f);
      float v2 = fexp2((a2.z > 0) ? fmaxf(e2, 0.01f * e2) : -256.f);
      float v3 = fexp2((a2.w > 0) ? fmaxf(e3, 0.01f * e3) : -256.f);
      float v4 = fexp2((a3.x > 0) ? fmaxf(e4, 0.01f * e4) : -256.f);
      float v5 = fexp2((a3.y > 0) ? fmaxf(e5, 0.01f * e5) : -256.f);
      float v6 = fexp2((a3.z > 0) ? fmaxf(e6, 0.01f * e6) : -256.f);
      float v7 = fexp2((a3.w > 0) ? fmaxf(e7, 0.01f * e7) : -256.f);
      w1.u[0] = __builtin_amdgcn_perm(__float_as_uint(v1), __float_as_uint(v0), 0x07060302u);
      w1.u[1] = __builtin_amdgcn_perm(__float_as_uint(v3), __float_as_uint(v2), 0x07060302u);
      w1.u[2] = __builtin_amdgcn_perm(__float_as_uint(v5), __float_as_uint(v4), 0x07060302u);
      w1.u[3] = __builtin_amdgcn_perm(__float_as_uint(v7), __float_as_uint(v6), 0x07060302u);
    }

#pragma unroll
    for (int nf = 0; nf < 4; ++nf)
      acc[nf] = __builtin_amdgcn_mfma_f32_16x16x32_bf16(w0.v, B0[nf], acc[nf], 0, 0, 0);
    accS = __builtin_amdgcn_mfma_f32_16x16x32_bf16(w0.v, ones, accS, 0, 0, 0);
#pragma unroll
    for (int nf = 0; nf < 4; ++nf)
      acc[nf] = __builtin_amdgcn_mfma_f32_16x16x32_bf16(w1.v, B1[nf], acc[nf], 0, 0, 0);
    accS = __builtin_amdgcn_mfma_f32_16x16x32_bf16(w1.v, ones, accS, 0, 0, 0);

    if (c + 1 < NCH) {  // rotate B-frags: WAR on MFMA reads keeps order; barrier drains
#pragma unroll
      for (int nf = 0; nf < 4; ++nf) {
        B0[nf] = *(const bf16x8*)(hbase + (long)nf * (16 * GN) + (c + 1) * 256 + jo0);
        B1[nf] = *(const bf16x8*)(hbase + (long)nf * (16 * GN) + (c + 1) * 256 + jo1);
      }
    }
    __syncthreads();  // drains async stage c+1 + B rotation loads
  }

  // epilogue: overlay pb/sb on smem (all adj reads done before last barrier)
#pragma unroll
  for (int nf = 0; nf < 4; ++nf)
#pragma unroll
    for (int rgi = 0; rgi < 4; ++rgi)
      pb[(wv * 16 + quad * 4 + rgi) * 68 + nf * 16 + tn] = acc[nf][rgi];
  if (tn == 0) {
#pragma unroll
    for (int rgi = 0; rgi < 4; ++rgi)
      sb[wv * 16 + quad * 4 + rgi] = accS[rgi];
  }
  __syncthreads();
  for (int t = tid; t < 16 * OD; t += 256) {
    int rr = t >> 6, cc = t & 63;
    float num = pb[(0 * 16 + rr) * 68 + cc] + pb[(1 * 16 + rr) * 68 + cc] +
                pb[(2 * 16 + rr) * 68 + cc] + pb[(3 * 16 + rr) * 68 + cc];
    pn[((long)js * GN + i0 + rr) * OD + cc] = num;
  }
  if (tid < 16) {
    float den = sb[0 * 16 + tid] + sb[1 * 16 + tid] + sb[2 * 16 + tid] + sb[3 * 16 + tid];
    pd[(long)js * GN + i0 + tid] = den;
  }
}

// ---------------------------------------------------------------------------
// Kernel 3: combine the 2 j-slices: out = (pn0+pn1)/(pd0+pd1)
// ---------------------------------------------------------------------------
__global__ __launch_bounds__(256) void gat_k3(
    const float* __restrict__ pn, const float* __restrict__ pd,
    float* __restrict__ out)
{
  long t = (long)blockIdx.x * 256 + threadIdx.x;   // 0 .. GN*OD
  int i = (int)(t >> 6);
  float num = pn[t] + pn[(long)GN * OD + t];
  float den = pd[i] + pd[GN + i];
  out[t] = num / den;
}

extern "C" void kernel_launch(void* const* d_in, const int* in_sizes, int n_in,
                              void* d_out, int out_size, void* d_ws, size_t ws_size,
                              hipStream_t stream) {
  const float* input = (const float*)d_in[0];
  const int* adj     = (const int*)d_in[1];
  const float* W     = (const float*)d_in[2];
  const float* a     = (const float*)d_in[3];
  float* out = (float*)d_out;

  char* ws = (char*)d_ws;
  __hip_bfloat16* hT = (__hip_bfloat16*)ws;               // 1 MB
  float* f1p = (float*)(ws + (size_t)OD * GN * 2);        // 32 KB
  float* f2p = f1p + GN;                                  // 32 KB
  float* pn  = f2p + GN;                                  // 2 * 8192 * 64 * 4 = 4 MB
  float* pd  = pn + (size_t)2 * GN * OD;                  // 64 KB

  gat_k1<<<256, 256, 0, stream>>>(input, W, a, hT, f1p, f2p, out);
  gat_k2<<<1024, 256, 0, stream>>>(adj, hT, f1p, f2p, pn, pd);
  gat_k3<<<GN * OD / 256, 256, 0, stream>>>(pn, pd, out);
}